// Round 7
// baseline (375.379 us; speedup 1.0000x reference)
//
#include <hip/hip_runtime.h>

typedef float f4 __attribute__((ext_vector_type(4)));

// ---------------------------------------------------------------------------
// R7 DIAGNOSTIC BUILD: exact R6 structure, but the whole segment body runs
// TWICE in one dispatch (idempotent rewrite of the same output). Purpose:
// push this dispatch's duration above the harness's ~320us poison fills so
// it surfaces in the rocprof top-5 and we finally see FETCH/WRITE/LDS/VALU
// counters for THIS kernel. Counters read as 2x the real single-pass work.
// ---------------------------------------------------------------------------
__global__ __launch_bounds__(256) void emb_kernel(const float* __restrict__ x,
                                                  const int* __restrict__ lengths,
                                                  float* __restrict__ out) {
    __shared__ alignas(16) float lt[4 * 2064];   // 33 KB: 16-row buffer per wave
    __shared__ int wred[4];
    __shared__ int s_off;

    const int s = blockIdx.x;
    const int tid = threadIdx.x;

    // ---- exclusive prefix offset for this segment (general ragged case) ----
    int partial = 0;
    for (int i = tid; i < s; i += 256) partial += lengths[i];
    #pragma unroll
    for (int d = 32; d > 0; d >>= 1) partial += __shfl_xor(partial, d, 64);
    if ((tid & 63) == 0) wred[tid >> 6] = partial;
    __syncthreads();
    if (tid == 0) s_off = wred[0] + wred[1] + wred[2] + wred[3];
    __syncthreads();

    const int off = s_off;
    const int L = lengths[s];
    if (L <= 0) return;
    const float invL = 1.0f / (float)L;

    const float* __restrict__ xs = x + (size_t)off * 128;
    float* __restrict__ os = out + (size_t)off * 129;

    const int wave = tid >> 6;
    const int lane = tid & 63;
    float* __restrict__ lb = lt + wave * 2064;

    // fast path: off % 16 == 0 makes both streams 64B-line-aligned
    const int nt64 = ((off & 15) == 0) ? (L >> 6) : 0;   // 64-row block tiles

    #pragma unroll 1
    for (int pass = 0; pass < 2; ++pass) {
        if (nt64 > 0) {
            const f4* __restrict__ xs4 = (const f4*)xs;
            f4 a[8];
            {   // prologue: prefetch tile 0 (this wave's 16 rows = 512 f4)
                const f4* src = xs4 + (size_t)(16 * wave) * 32;
                #pragma unroll
                for (int p = 0; p < 8; ++p) a[p] = src[lane + 64 * p];
            }
            for (int t = 0; t < nt64; ++t) {
                const int r0 = 64 * t + 16 * wave;

                // scatter regs -> LDS in output layout (+1 col shift)
                #pragma unroll
                for (int p = 0; p < 8; ++p) {
                    const int q = lane + 64 * p;      // f4 index in 16x128 tile
                    const int r = q >> 5;
                    const int k = q & 31;
                    float* d = &lb[r * 129 + 1 + 4 * k];
                    d[0] = a[p].x; d[1] = a[p].y; d[2] = a[p].z; d[3] = a[p].w;
                }
                if (lane < 16) lb[lane * 129] = (float)(r0 + lane + 1) * invL;

                // software-prefetch next tile's loads
                if (t + 1 < nt64) {
                    const f4* src = xs4 + (size_t)(64 * (t + 1) + 16 * wave) * 32;
                    #pragma unroll
                    for (int p = 0; p < 8; ++p) a[p] = src[lane + 64 * p];
                }

                // drain: flat LDS read + full-line cached stores
                const f4* __restrict__ l4 = (const f4*)lb;
                f4* __restrict__ o4 = (f4*)(os + (size_t)r0 * 129);
                #pragma unroll
                for (int p = 0; p < 8; ++p)
                    o4[lane + 64 * p] = l4[lane + 64 * p];
                if (lane < 4)
                    o4[512 + lane] = l4[512 + lane];
            }
        }

        // tail rows / unaligned segment base: scalar fallback (general ragged)
        const int e0 = nt64 * 64 * 129;
        const int E = L * 129;
        for (int e = e0 + tid; e < E; e += 256) {
            const int row = e / 129;
            const int c = e - row * 129;
            os[e] = (c == 0) ? (float)(row + 1) * invL
                             : xs[(size_t)row * 128 + (c - 1)];
        }

        // compiler barrier: prevent cross-pass store elimination (keeps the
        // diagnostic 2x work real). No runtime cost.
        asm volatile("" ::: "memory");
    }
}

extern "C" void kernel_launch(void* const* d_in, const int* in_sizes, int n_in,
                              void* d_out, int out_size, void* d_ws, size_t ws_size,
                              hipStream_t stream) {
    const float* x = (const float*)d_in[0];
    const int* lengths = (const int*)d_in[1];
    const int n_seg = in_sizes[1];

    emb_kernel<<<n_seg, 256, 0, stream>>>(x, lengths, (float*)d_out);
}

// Round 8
// 216.372 us; speedup vs baseline: 1.7349x; 1.7349x over previous
//
#include <hip/hip_runtime.h>

typedef float f4 __attribute__((ext_vector_type(4)));

// ---------------------------------------------------------------------------
// One block per segment, 256 threads = 4 waves, barrier-free hot loop.
// Wave chunk = 16 rows (loads 8 KB / stores 8.25 KB, all 64B-line-aligned,
// wave-private LDS bounce absorbs the +1 column shift).
// R8: register prefetch depth 1 -> 3 (three named f4[8] sets, software-
// pipelined). A load set is issued 3 sub-iterations (~900 cy of issue work)
// before its consume, covering HBM read latency. Evidence: R7 doubled-pass
// showed identical structure runs at 6.3 TB/s through-core when reads hit L3
// (171 us/pass) vs 4.85 TB/s with HBM reads (222 us) -> latency-exposure
// limited, not traffic (FETCH/WRITE = exactly ideal) and not LDS/VALU.
// ---------------------------------------------------------------------------
__global__ __launch_bounds__(256) void emb_kernel(const float* __restrict__ x,
                                                  const int* __restrict__ lengths,
                                                  float* __restrict__ out) {
    __shared__ alignas(16) float lt[4 * 2064];   // 33 KB: 16-row buffer per wave
    __shared__ int wred[4];
    __shared__ int s_off;

    const int s = blockIdx.x;
    const int tid = threadIdx.x;

    // ---- exclusive prefix offset for this segment (general ragged case) ----
    int partial = 0;
    for (int i = tid; i < s; i += 256) partial += lengths[i];
    #pragma unroll
    for (int d = 32; d > 0; d >>= 1) partial += __shfl_xor(partial, d, 64);
    if ((tid & 63) == 0) wred[tid >> 6] = partial;
    __syncthreads();
    if (tid == 0) s_off = wred[0] + wred[1] + wred[2] + wred[3];
    __syncthreads();

    const int off = s_off;
    const int L = lengths[s];
    if (L <= 0) return;
    const float invL = 1.0f / (float)L;

    const float* __restrict__ xs = x + (size_t)off * 128;
    float* __restrict__ os = out + (size_t)off * 129;

    const int wave = tid >> 6;
    const int lane = tid & 63;
    float* __restrict__ lb = lt + wave * 2064;

    // fast path: off % 16 == 0 makes both streams 64B-line-aligned
    const int nt64 = ((off & 15) == 0) ? (L >> 6) : 0;   // 64-row block tiles

    if (nt64 > 0) {
        const f4* __restrict__ xs4 = (const f4*)xs;
        f4 a0[8], a1[8], a2[8];

#define LOADSET(A, u)                                                          \
        do {                                                                   \
            if ((u) < nt64) {                                                  \
                const f4* _src = xs4 + (size_t)(64 * (u) + 16 * wave) * 32;    \
                _Pragma("unroll")                                              \
                for (int p = 0; p < 8; ++p) A[p] = _src[lane + 64 * p];        \
            }                                                                  \
        } while (0)

#define CONSUME(A, u)                                                          \
        do {                                                                   \
            if ((u) < nt64) {                                                  \
                const int r0 = 64 * (u) + 16 * wave;                           \
                _Pragma("unroll")                                              \
                for (int p = 0; p < 8; ++p) {                                  \
                    const int q = lane + 64 * p;                               \
                    float* d = &lb[(q >> 5) * 129 + 1 + ((q & 31) << 2)];      \
                    d[0] = A[p].x; d[1] = A[p].y; d[2] = A[p].z; d[3] = A[p].w;\
                }                                                              \
                if (lane < 16) lb[lane * 129] = (float)(r0 + lane + 1) * invL; \
                const f4* __restrict__ l4 = (const f4*)lb;                     \
                f4* __restrict__ o4 = (f4*)(os + (size_t)r0 * 129);            \
                _Pragma("unroll")                                              \
                for (int p = 0; p < 8; ++p)                                    \
                    o4[lane + 64 * p] = l4[lane + 64 * p];                     \
                if (lane < 4) o4[512 + lane] = l4[512 + lane];                 \
            }                                                                  \
        } while (0)

        LOADSET(a0, 0);
        LOADSET(a1, 1);
        LOADSET(a2, 2);

        #pragma unroll 1
        for (int t = 0; t < nt64; t += 3) {
            CONSUME(a0, t);     LOADSET(a0, t + 3);
            CONSUME(a1, t + 1); LOADSET(a1, t + 4);
            CONSUME(a2, t + 2); LOADSET(a2, t + 5);
        }
#undef LOADSET
#undef CONSUME
    }

    // tail rows / unaligned segment base: scalar fallback (general ragged)
    const int e0 = nt64 * 64 * 129;
    const int E = L * 129;
    for (int e = e0 + tid; e < E; e += 256) {
        const int row = e / 129;
        const int c = e - row * 129;
        os[e] = (c == 0) ? (float)(row + 1) * invL
                         : xs[(size_t)row * 128 + (c - 1)];
    }
}

extern "C" void kernel_launch(void* const* d_in, const int* in_sizes, int n_in,
                              void* d_out, int out_size, void* d_ws, size_t ws_size,
                              hipStream_t stream) {
    const float* x = (const float*)d_in[0];
    const int* lengths = (const int*)d_in[1];
    const int n_seg = in_sizes[1];

    emb_kernel<<<n_seg, 256, 0, stream>>>(x, lengths, (float*)d_out);
}